// Round 5
// baseline (409.739 us; speedup 1.0000x reference)
//
#include <hip/hip_runtime.h>

#define L_LEN 131072
#define NB    2048     // 64-pos attention blocks
#define NT    1024     // 128-pos GEMM tiles

typedef unsigned short u16;
typedef __attribute__((ext_vector_type(4))) float f32x4;
typedef __attribute__((ext_vector_type(8))) short s16x8;
typedef __attribute__((ext_vector_type(4))) short s16x4;

// ---- ws byte offsets ----
#define WS_OUTT  0ull          // u16[L*256]  conv out, [pos][ch]; becomes hT in-place
#define WS_QT    67108864ull   // u16[L*128]  qT [pos][ch]
#define WS_PSUM  100663296ull  // float[256*1024]
#define WS_PSQ   101711872ull
#define WS_MEAN  102760448ull
#define WS_RSTD  102761472ull
#define WS_WFFB  102762496ull  // short[256*768] (k = t*256+c)
#define WS_WQKB  103155712ull  // short[256*256] rs-folded [Wq;Wk]
#define WS_WVB   103286784ull  // short[128*256]
#define WS_WOB   103352320ull  // short[256*128]
#define WS_WCB   103417856ull  // short[256*256]
#define WS_BQKP  103548928ull  // float[256]
// d_out regions (consumed before k_wc overwrites d_out):
//   v  u16[128*L] at byte 0 ; kT u16[L*128] at byte 33554432

__device__ __forceinline__ u16 f2bf(float v){
  union { float f; unsigned u; } a; a.f = v;
  unsigned r = a.u + 0x7fffu + ((a.u >> 16) & 1u);
  return (u16)(r >> 16);
}
__device__ __forceinline__ float bf2f(u16 u){
  union { unsigned u; float f; } a; a.u = ((unsigned)u) << 16; return a.f;
}
__device__ __forceinline__ unsigned cvtpk(float a, float b){
  unsigned r;
  asm("v_cvt_pk_bf16_f32 %0, %1, %2" : "=v"(r) : "v"(a), "v"(b));
  return r;
}
__device__ __forceinline__ f32x4 mfma16(s16x8 a, s16x8 b, f32x4 c){
  return __builtin_amdgcn_mfma_f32_16x16x32_bf16(a, b, c, 0, 0, 0);
}
__device__ __forceinline__ s16x8 ld8(const void* p){ return *(const s16x8*)p; }

// ---------------- K0: weight prep (fp32 -> bf16) ----------------
__global__ __launch_bounds__(256) void k_prep(
    const float* __restrict__ Wff, const float* __restrict__ Wv,
    const float* __restrict__ Wo,  const float* __restrict__ Wc,
    short* __restrict__ wffb, short* __restrict__ wvb,
    short* __restrict__ wob,  short* __restrict__ wcb)
{
  int i = blockIdx.x * 256 + threadIdx.x;
  if (i < 196608){
    int o = i / 768, kk = i % 768;
    int t = kk >> 8, c = kk & 255;
    wffb[i] = (short)f2bf(Wff[(o*256 + c)*3 + t]);
  } else if (i < 229376){ int j = i - 196608; wvb[j] = (short)f2bf(Wv[j]); }
  else if (i < 262144){ int j = i - 229376; wob[j] = (short)f2bf(Wo[j]); }
  else if (i < 327680){ int j = i - 262144; wcb[j] = (short)f2bf(Wc[j]); }
}

// ---------------- K1: dilated conv as GEMM -> outT[pos][ch] + stats ----------------
// tile: 128 och x 128 pos (grid 2048: och-half pairs 8 apart -> same XCD for
// window L2 reuse). 8 waves = 4 och-groups(32) x 2 pos-halves(64): acc[2][4]=32 regs.
// Tap-shared window (256 pos x 32 ch per chunk), double-buffered LDS.
__global__ __launch_bounds__(512, 4) void k_conv(
    const float* __restrict__ x, const short* __restrict__ wffb,
    const float* __restrict__ bff, u16* __restrict__ outT,
    float* __restrict__ psum, float* __restrict__ psq)
{
  __shared__ u16 xs[2*256*40];         // 40KB
  const int bid = blockIdx.x;
  const int oh = (bid >> 3) & 1;                  // och half (0/1)
  const int pt = ((bid >> 4) << 3) | (bid & 7);   // pos tile 0..1023
  const int l0 = pt * 128;
  const int tid = threadIdx.x;
  const int w = tid >> 6, lane = tid & 63, p = lane & 15, g = lane >> 4;
  const int wo = w >> 1, wp = w & 1;              // wave: och-group, pos-half
  const int cl = tid >> 4, posq = tid & 15;       // staging roles

  // prologue: stage chunk 0 into buf 0
  {
    #pragma unroll
    for (int u = 0; u < 4; ++u){
      const int row = 64*u + 4*posq;
      const long gp = (long)l0 - 64 + row;
      f32x4 v = {0.f,0.f,0.f,0.f};
      if (gp >= 0 && gp + 4 <= L_LEN)
        v = *(const f32x4*)(x + (size_t)cl*L_LEN + gp);
      const unsigned r01 = cvtpk(v[0], v[1]);
      const unsigned r23 = cvtpk(v[2], v[3]);
      xs[(row+0)*40 + (cl ^ (8*(((row+0)>>2)&3)))] = (u16)(r01 & 0xffffu);
      xs[(row+1)*40 + (cl ^ (8*(((row+1)>>2)&3)))] = (u16)(r01 >> 16);
      xs[(row+2)*40 + (cl ^ (8*(((row+2)>>2)&3)))] = (u16)(r23 & 0xffffu);
      xs[(row+3)*40 + (cl ^ (8*(((row+3)>>2)&3)))] = (u16)(r23 >> 16);
    }
  }
  __syncthreads();

  f32x4 acc[2][4] = {};
  #pragma unroll 1
  for (int cg = 0; cg < 8; ++cg){
    const int cur = (cg & 1) * 10240;
    const int nxt = ((cg + 1) & 1) * 10240;
    f32x4 vv[4];
    const bool have = (cg < 7);
    if (have){
      #pragma unroll
      for (int u = 0; u < 4; ++u){
        const int row = 64*u + 4*posq;
        const long gp = (long)l0 - 64 + row;
        vv[u] = f32x4{0.f,0.f,0.f,0.f};
        if (gp >= 0 && gp + 4 <= L_LEN)
          vv[u] = *(const f32x4*)(x + (size_t)((cg+1)*32 + cl)*L_LEN + gp);
      }
    }
    // MFMA phase: 3 taps x 4 fn x 2 fm = 24 MFMAs/wave
    #pragma unroll
    for (int t = 0; t < 3; ++t){
      s16x8 a0 = ld8(wffb + (size_t)(128*oh + 32*wo +      p)*768 + t*256 + cg*32 + 8*g);
      s16x8 a1 = ld8(wffb + (size_t)(128*oh + 32*wo + 16 + p)*768 + t*256 + cg*32 + 8*g);
      #pragma unroll
      for (int fn = 0; fn < 4; ++fn){
        const int row = 64*t + 64*wp + 16*fn + p;
        s16x8 b = ld8(&xs[cur + row*40 + ((8*g) ^ (8*((row>>2)&3)))]);
        acc[0][fn] = mfma16(a0, b, acc[0][fn]);
        acc[1][fn] = mfma16(a1, b, acc[1][fn]);
      }
    }
    if (have){
      #pragma unroll
      for (int u = 0; u < 4; ++u){
        const int row = 64*u + 4*posq;
        const unsigned r01 = cvtpk(vv[u][0], vv[u][1]);
        const unsigned r23 = cvtpk(vv[u][2], vv[u][3]);
        xs[nxt + (row+0)*40 + (cl ^ (8*(((row+0)>>2)&3)))] = (u16)(r01 & 0xffffu);
        xs[nxt + (row+1)*40 + (cl ^ (8*(((row+1)>>2)&3)))] = (u16)(r01 >> 16);
        xs[nxt + (row+2)*40 + (cl ^ (8*(((row+2)>>2)&3)))] = (u16)(r23 & 0xffffu);
        xs[nxt + (row+3)*40 + (cl ^ (8*(((row+3)>>2)&3)))] = (u16)(r23 >> 16);
      }
    }
    __syncthreads();
  }

  // epilogue: bias+relu, store outT, stats (combine the two pos-half waves via LDS)
  float* sred = (float*)xs;   // 128 och x {sum,sq}; xs dead (post-barrier)
  float ssum[2][4], ssq[2][4];
  #pragma unroll
  for (int fm = 0; fm < 2; ++fm){
    const int ol = 32*wo + 16*fm + 4*g;           // local och base (0..127)
    #pragma unroll
    for (int i = 0; i < 4; ++i){ ssum[fm][i] = 0.f; ssq[fm][i] = 0.f; }
    #pragma unroll
    for (int fn = 0; fn < 4; ++fn){
      const int pos = l0 + 64*wp + 16*fn + p;
      s16x4 pk;
      #pragma unroll
      for (int i = 0; i < 4; ++i){
        float val = fmaxf(acc[fm][fn][i] + bff[128*oh + ol + i], 0.f);
        pk[i] = (short)f2bf(val);
        ssum[fm][i] += val; ssq[fm][i] += val*val;
      }
      *(s16x4*)(outT + (size_t)pos*256 + 128*oh + ol) = pk;
    }
    #pragma unroll
    for (int i = 0; i < 4; ++i){
      #pragma unroll
      for (int d = 1; d < 16; d <<= 1){
        ssum[fm][i] += __shfl_xor(ssum[fm][i], d, 16);
        ssq[fm][i]  += __shfl_xor(ssq[fm][i],  d, 16);
      }
    }
  }
  __syncthreads();
  if (wp == 1 && p == 0){
    #pragma unroll
    for (int fm = 0; fm < 2; ++fm){
      const int ol = 32*wo + 16*fm + 4*g;
      #pragma unroll
      for (int i = 0; i < 4; ++i){
        sred[(ol+i)*2+0] = ssum[fm][i];
        sred[(ol+i)*2+1] = ssq[fm][i];
      }
    }
  }
  __syncthreads();
  if (wp == 0 && p == 0){
    #pragma unroll
    for (int fm = 0; fm < 2; ++fm){
      const int ol = 32*wo + 16*fm + 4*g;
      #pragma unroll
      for (int i = 0; i < 4; ++i){
        const int og = 128*oh + ol + i;
        psum[(size_t)og*NT + pt] = ssum[fm][i] + sred[(ol+i)*2+0];
        psq [(size_t)og*NT + pt] = ssq[fm][i]  + sred[(ol+i)*2+1];
      }
    }
  }
}

// ---------------- K2: finalize stats ----------------
__global__ __launch_bounds__(256) void k_stats(
    const float* __restrict__ psum, const float* __restrict__ psq,
    float* __restrict__ mean, float* __restrict__ rstd)
{
  __shared__ float ss[256], sq[256];
  const int ch = blockIdx.x, tid = threadIdx.x;
  float a = 0.f, b = 0.f;
  for (int j = tid; j < NT; j += 256){ a += psum[(size_t)ch*NT + j]; b += psq[(size_t)ch*NT + j]; }
  ss[tid] = a; sq[tid] = b;
  __syncthreads();
  for (int st = 128; st > 0; st >>= 1){
    if (tid < st){ ss[tid] += ss[tid+st]; sq[tid] += sq[tid+st]; }
    __syncthreads();
  }
  if (tid == 0){
    float m = ss[0] / (float)L_LEN;
    float v = sq[0] / (float)L_LEN - m*m;
    mean[ch] = m;
    rstd[ch] = rsqrtf(v + 1e-5f);
  }
}

// ---------------- K3: fold norm into Wq/Wk ----------------
__global__ __launch_bounds__(256) void k_adj(
    const float* __restrict__ Wq, const float* __restrict__ Wk,
    const float* __restrict__ bq, const float* __restrict__ bk,
    const float* __restrict__ mean, const float* __restrict__ rstd,
    short* __restrict__ wqkb, float* __restrict__ bqkp)
{
  __shared__ float red[256];
  const int o = blockIdx.x, c = threadIdx.x;
  const float* src = (o < 128) ? (Wq + (size_t)o*256) : (Wk + (size_t)(o-128)*256);
  const float bias = (o < 128) ? bq[o] : bk[o-128];
  float wv = src[c] * rstd[c];
  wqkb[o*256 + c] = (short)f2bf(wv);
  red[c] = wv * mean[c];
  __syncthreads();
  for (int st = 128; st > 0; st >>= 1){
    if (c < st) red[c] += red[c+st];
    __syncthreads();
  }
  if (c == 0) bqkp[o] = bias - red[0];
}

// ---------------- K4: v = Wv @ f + bv -> v[128][L] ----------------
// 512 thr, wave = 16 cv x 128 pos: acc[8] = 32 regs. Double-buffered.
__global__ __launch_bounds__(512, 4) void k_v(
    const float* __restrict__ fin, const short* __restrict__ wvb,
    const float* __restrict__ bv, u16* __restrict__ vout)
{
  __shared__ u16 xs[2*128*40];         // 20KB
  const int wg = blockIdx.x, l0 = wg * 128;
  const int tid = threadIdx.x;
  const int w = tid >> 6, lane = tid & 63, p = lane & 15, g = lane >> 4;
  const int cl = tid >> 4, posq = tid & 15;   // 32 ch x 16 pos-groups (8 rows each)

  {
    #pragma unroll
    for (int u = 0; u < 2; ++u){
      const int row = 8*posq + 4*u;
      f32x4 v = *(const f32x4*)(fin + (size_t)cl*L_LEN + l0 + row);
      const unsigned r01 = cvtpk(v[0], v[1]);
      const unsigned r23 = cvtpk(v[2], v[3]);
      xs[(row+0)*40 + (cl ^ (8*(((row+0)>>2)&3)))] = (u16)(r01 & 0xffffu);
      xs[(row+1)*40 + (cl ^ (8*(((row+1)>>2)&3)))] = (u16)(r01 >> 16);
      xs[(row+2)*40 + (cl ^ (8*(((row+2)>>2)&3)))] = (u16)(r23 & 0xffffu);
      xs[(row+3)*40 + (cl ^ (8*(((row+3)>>2)&3)))] = (u16)(r23 >> 16);
    }
  }
  __syncthreads();

  f32x4 acc[8] = {};
  #pragma unroll 1
  for (int cg = 0; cg < 8; ++cg){
    const int cur = (cg & 1) * 5120;
    const int nxt = ((cg + 1) & 1) * 5120;
    f32x4 vv[2];
    const bool have = (cg < 7);
    if (have){
      #pragma unroll
      for (int u = 0; u < 2; ++u){
        const int row = 8*posq + 4*u;
        vv[u] = *(const f32x4*)(fin + (size_t)((cg+1)*32 + cl)*L_LEN + l0 + row);
      }
    }
    s16x8 af = ld8(wvb + (size_t)(16*w + p)*256 + cg*32 + 8*g);
    #pragma unroll
    for (int fn = 0; fn < 8; ++fn){
      const int row = 16*fn + p;
      s16x8 b = ld8(&xs[cur + row*40 + ((8*g) ^ (8*((row>>2)&3)))]);
      acc[fn] = mfma16(af, b, acc[fn]);
    }
    if (have){
      #pragma unroll
      for (int u = 0; u < 2; ++u){
        const int row = 8*posq + 4*u;
        const unsigned r01 = cvtpk(vv[u][0], vv[u][1]);
        const unsigned r23 = cvtpk(vv[u][2], vv[u][3]);
        xs[nxt + (row+0)*40 + (cl ^ (8*(((row+0)>>2)&3)))] = (u16)(r01 & 0xffffu);
        xs[nxt + (row+1)*40 + (cl ^ (8*(((row+1)>>2)&3)))] = (u16)(r01 >> 16);
        xs[nxt + (row+2)*40 + (cl ^ (8*(((row+2)>>2)&3)))] = (u16)(r23 & 0xffffu);
        xs[nxt + (row+3)*40 + (cl ^ (8*(((row+3)>>2)&3)))] = (u16)(r23 >> 16);
      }
    }
    __syncthreads();
  }
  #pragma unroll
  for (int fn = 0; fn < 8; ++fn){
    #pragma unroll
    for (int i = 0; i < 4; ++i){
      const int cv = 16*w + 4*g + i;
      vout[(size_t)cv*L_LEN + l0 + 16*fn + p] = f2bf(acc[fn][i] + bv[cv]);
    }
  }
}

// ---------------- K5: [q;k] = Wqk' @ out + bqk' -> qT, kT ----------------
__global__ __launch_bounds__(512, 4) void k_qk(
    const u16* __restrict__ outT, const short* __restrict__ wqkb,
    const float* __restrict__ bqkp, u16* __restrict__ qT, u16* __restrict__ kT)
{
  extern __shared__ u16 tile[];        // [128 pos][256 ch] swizzled, 64KB
  const int wg = blockIdx.x, l0 = wg * 128;
  const int tid = threadIdx.x;
  const int w = tid >> 6, lane = tid & 63, p = lane & 15, g = lane >> 4;
  #pragma unroll
  for (int rep = 0; rep < 8; ++rep){
    const int idx = rep*512 + tid;
    const int r = idx >> 5, cc = idx & 31;
    s16x8 vput = ld8(outT + (size_t)(l0 + r)*256 + cc*8);
    *(s16x8*)(&tile[r*256 + ((cc*8) ^ ((r&7)<<3))]) = vput;
  }
  __syncthreads();
  f32x4 acc[2][8] = {};
  #pragma unroll
  for (int kk = 0; kk < 8; ++kk){
    s16x8 af[2];
    af[0] = ld8(wqkb + (size_t)(32*w +      p)*256 + 32*kk + 8*g);
    af[1] = ld8(wqkb + (size_t)(32*w + 16 + p)*256 + 32*kk + 8*g);
    #pragma unroll
    for (int fn = 0; fn < 8; ++fn){
      const int r = 16*fn + p;
      s16x8 b = ld8(&tile[r*256 + ((32*kk + 8*g) ^ ((r&7)<<3))]);
      acc[0][fn] = mfma16(af[0], b, acc[0][fn]);
      acc[1][fn] = mfma16(af[1], b, acc[1][fn]);
    }
  }
  #pragma unroll
  for (int fm = 0; fm < 2; ++fm){
    const int R0 = 32*w + 16*fm + 4*g;
    #pragma unroll
    for (int fn = 0; fn < 8; ++fn){
      s16x4 pk;
      #pragma unroll
      for (int i = 0; i < 4; ++i) pk[i] = (short)f2bf(acc[fm][fn][i] + bqkp[R0+i]);
      const size_t row = (size_t)(l0 + 16*fn + p);
      if (R0 < 128) *(s16x4*)(qT + row*128 + R0)       = pk;
      else          *(s16x4*)(kT + row*128 + R0 - 128) = pk;
    }
  }
}

// ---------------- K6: attention per 64-block + Wo; h in-place over outT ----------------
__global__ __launch_bounds__(256, 4) void k_attn(
    const u16* __restrict__ qT, const u16* __restrict__ kT,
    const u16* __restrict__ vg, const short* __restrict__ wob,
    const float* __restrict__ bo, const float* __restrict__ mask,
    u16* __restrict__ outT)
{
  __shared__ u16 klds[16384];          // 32KB: k-window; overlays: p [0,8K), rov [8K,16K)
  __shared__ float maskw[128];
  const int tid = threadIdx.x;
  const int w = tid >> 6, lane = tid & 63, p = lane & 15, g = lane >> 4;
  const int n = blockIdx.x, s = n * 64;
  const float SCALE = 0.08838834764831845f;

  #pragma unroll
  for (int rep = 0; rep < 8; ++rep){
    const int idx = rep*256 + tid;
    const int m = idx >> 4, cc = idx & 15;
    const int gpos = s - 32 + m;
    s16x8 vput = {};
    if (gpos >= 0 && gpos < L_LEN) vput = ld8(kT + (size_t)gpos*128 + cc*8);
    *(s16x8*)(&klds[m*128 + ((cc*8) ^ ((m&7)<<3))]) = vput;
  }
  if (tid < 128){
    const int gp = s - 32 + tid;
    maskw[tid] = (gp >= 0 && gp < L_LEN) ? mask[gp] : 0.f;
  }
  __syncthreads();

  f32x4 e[8] = {};
  #pragma unroll
  for (int kk = 0; kk < 4; ++kk){
    s16x8 aq = ld8(qT + (size_t)(s + 16*w + p)*128 + 32*kk + 8*g);
    #pragma unroll
    for (int fn = 0; fn < 8; ++fn){
      const int m = 16*fn + p;
      s16x8 b = ld8(&klds[m*128 + ((32*kk + 8*g) ^ ((m&7)<<3))]);
      e[fn] = mfma16(aq, b, e[fn]);
    }
  }
  float M[4] = {-1e30f,-1e30f,-1e30f,-1e30f};
  float S[4] = {0.f,0.f,0.f,0.f};
  #pragma unroll
  for (int fn = 0; fn < 8; ++fn){
    #pragma unroll
    for (int i = 0; i < 4; ++i){
      const int mm = 16*fn + p;
      const int l_ = 16*w + 4*g + i;
      const int d = mm - l_;
      const float fmv = (d >= 0 && d < 64) ? maskw[mm] : 0.f;
      const float z = e[fn][i]*SCALE + __logf(fmv + 1e-6f);
      e[fn][i] = z;
      M[i] = fmaxf(M[i], z);
    }
  }
  #pragma unroll
  for (int i = 0; i < 4; ++i){
    #pragma unroll
    for (int d = 1; d < 16; d <<= 1) M[i] = fmaxf(M[i], __shfl_xor(M[i], d, 16));
  }
  #pragma unroll
  for (int fn = 0; fn < 8; ++fn){
    #pragma unroll
    for (int i = 0; i < 4; ++i){
      const float pv = __expf(e[fn][i] - M[i]);
      e[fn][i] = pv;
      S[i] += pv;
    }
  }
  #pragma unroll
  for (int i = 0; i < 4; ++i){
    #pragma unroll
    for (int d = 1; d < 16; d <<= 1) S[i] += __shfl_xor(S[i], d, 16);
  }
  float rinv[4];
  #pragma unroll
  for (int i = 0; i < 4; ++i) rinv[i] = 1.f / S[i];
  __syncthreads();
  #pragma unroll
  for (int fn = 0; fn < 8; ++fn){
    #pragma unroll
    for (int i = 0; i < 4; ++i){
      const int mm = 16*fn + p;
      const int l_ = 16*w + 4*g + i;
      const int d = mm - l_;
      const float fmv = (d >= 0 && d < 64) ? maskw[mm] : 0.f;
      klds[l_*128 + (mm ^ ((l_&7)<<3))] = f2bf(e[fn][i] * rinv[i] * fmv);
    }
  }
  __syncthreads();

  f32x4 accp[2][4] = {};
  #pragma unroll
  for (int kk = 0; kk < 4; ++kk){
    int gp0 = s - 32 + 32*kk + 8*g;
    gp0 = max(0, min(gp0, L_LEN - 8));
    s16x8 a0 = ld8(vg + (size_t)(32*w +      p)*L_LEN + gp0);
    s16x8 a1 = ld8(vg + (size_t)(32*w + 16 + p)*L_LEN + gp0);
    #pragma unroll
    for (int fn = 0; fn < 4; ++fn){
      const int l_ = 16*fn + p;
      s16x8 b = ld8(&klds[l_*128 + ((32*kk + 8*g) ^ ((l_&7)<<3))]);
      accp[0][fn] = mfma16(a0, b, accp[0][fn]);
      accp[1][fn] = mfma16(a1, b, accp[1][fn]);
    }
  }
  #pragma unroll
  for (int fm = 0; fm < 2; ++fm){
    #pragma unroll
    for (int fn = 0; fn < 4; ++fn){
      const int l_ = 16*fn + p;
      s16x4 pk;
      #pragma unroll
      for (int i = 0; i < 4; ++i) pk[i] = (short)f2bf(fmaxf(accp[fm][fn][i], 0.f));
      const int cv0 = 32*w + 16*fm + 4*g;
      *(s16x4*)(&klds[8192 + l_*128 + (cv0 ^ ((l_&7)<<3))]) = pk;
    }
  }
  __syncthreads();

  f32x4 acco[4][4] = {};
  #pragma unroll
  for (int kk = 0; kk < 4; ++kk){
    s16x8 a[4];
    #pragma unroll
    for (int fm = 0; fm < 4; ++fm)
      a[fm] = ld8(wob + (size_t)(64*w + 16*fm + p)*128 + 32*kk + 8*g);
    #pragma unroll
    for (int fn = 0; fn < 4; ++fn){
      const int l_ = 16*fn + p;
      s16x8 b = ld8(&klds[8192 + l_*128 + ((32*kk + 8*g) ^ ((l_&7)<<3))]);
      #pragma unroll
      for (int fm = 0; fm < 4; ++fm) acco[fm][fn] = mfma16(a[fm], b, acco[fm][fn]);
    }
  }
  #pragma unroll
  for (int fm = 0; fm < 4; ++fm){
    const int o0 = 64*w + 16*fm + 4*g;
    #pragma unroll
    for (int fn = 0; fn < 4; ++fn){
      const int l_ = 16*fn + p;
      const float pml = maskw[32 + l_];
      u16* hp = outT + (size_t)(s + l_)*256 + o0;
      s16x4 res = *(const s16x4*)hp;
      s16x4 pk;
      #pragma unroll
      for (int i = 0; i < 4; ++i){
        float hv = (acco[fm][fn][i] + bo[o0+i]) * pml + bf2f((u16)res[i]);
        pk[i] = (short)f2bf(hv);
      }
      *(s16x4*)hp = pk;
    }
  }
}

// ---------------- K7: y = Wc @ h + bc; dout = (x + y) * mask ----------------
__global__ __launch_bounds__(512, 4) void k_wc(
    const u16* __restrict__ hT, const short* __restrict__ wcb,
    const float* __restrict__ bc, const float* __restrict__ x,
    const float* __restrict__ mask, float* __restrict__ dout)
{
  extern __shared__ u16 tile[];
  const int wg = blockIdx.x, l0 = wg * 128;
  const int tid = threadIdx.x;
  const int w = tid >> 6, lane = tid & 63, p = lane & 15, g = lane >> 4;
  #pragma unroll
  for (int rep = 0; rep < 8; ++rep){
    const int idx = rep*512 + tid;
    const int r = idx >> 5, cc = idx & 31;
    s16x8 vput = ld8(hT + (size_t)(l0 + r)*256 + cc*8);
    *(s16x8*)(&tile[r*256 + ((cc*8) ^ ((r&7)<<3))]) = vput;
  }
  __syncthreads();
  f32x4 acc[2][8] = {};
  #pragma unroll
  for (int kk = 0; kk < 8; ++kk){
    s16x8 af[2];
    af[0] = ld8(wcb + (size_t)(32*w +      p)*256 + 32*kk + 8*g);
    af[1] = ld8(wcb + (size_t)(32*w + 16 + p)*256 + 32*kk + 8*g);
    #pragma unroll
    for (int fn = 0; fn < 8; ++fn){
      const int r = 16*fn + p;
      s16x8 b = ld8(&tile[r*256 + ((32*kk + 8*g) ^ ((r&7)<<3))]);
      acc[0][fn] = mfma16(af[0], b, acc[0][fn]);
      acc[1][fn] = mfma16(af[1], b, acc[1][fn]);
    }
  }
  #pragma unroll
  for (int fm = 0; fm < 2; ++fm){
    const int o0 = 32*w + 16*fm + 4*g;
    #pragma unroll
    for (int fn = 0; fn < 8; ++fn){
      const int pos = l0 + 16*fn + p;
      const float mk = mask[pos];
      #pragma unroll
      for (int i = 0; i < 4; ++i){
        const size_t idx = (size_t)(o0+i)*L_LEN + pos;
        dout[idx] = (x[idx] + acc[fm][fn][i] + bc[o0+i]) * mk;
      }
    }
  }
}

extern "C" void kernel_launch(void* const* d_in, const int* in_sizes, int n_in,
                              void* d_out, int out_size, void* d_ws, size_t ws_size,
                              hipStream_t stream)
{
  (void)in_sizes; (void)n_in; (void)out_size; (void)ws_size;
  const float* x    = (const float*)d_in[0];
  const float* f    = (const float*)d_in[1];
  const float* mask = (const float*)d_in[2];
  const float* Wff  = (const float*)d_in[3];
  const float* bff  = (const float*)d_in[4];
  const float* Wq   = (const float*)d_in[5];
  const float* bq   = (const float*)d_in[6];
  const float* Wk   = (const float*)d_in[7];
  const float* bk   = (const float*)d_in[8];
  const float* Wv   = (const float*)d_in[9];
  const float* bv   = (const float*)d_in[10];
  const float* Wo   = (const float*)d_in[11];
  const float* bo   = (const float*)d_in[12];
  const float* Wc   = (const float*)d_in[13];
  const float* bc   = (const float*)d_in[14];

  char* ws = (char*)d_ws;
  u16*   outT = (u16*)(ws + WS_OUTT);
  u16*   qT   = (u16*)(ws + WS_QT);
  float* psum = (float*)(ws + WS_PSUM);
  float* psq  = (float*)(ws + WS_PSQ);
  float* mean = (float*)(ws + WS_MEAN);
  float* rstd = (float*)(ws + WS_RSTD);
  short* wffb = (short*)(ws + WS_WFFB);
  short* wqkb = (short*)(ws + WS_WQKB);
  short* wvb  = (short*)(ws + WS_WVB);
  short* wob  = (short*)(ws + WS_WOB);
  short* wcb  = (short*)(ws + WS_WCB);
  float* bqkp = (float*)(ws + WS_BQKP);

  u16* vbuf = (u16*)d_out;                       // v[128][L]
  u16* ktb  = (u16*)((char*)d_out + 33554432);   // kT[L][128]

  (void)hipFuncSetAttribute((const void*)k_qk,
                            hipFuncAttributeMaxDynamicSharedMemorySize, 65536);
  (void)hipFuncSetAttribute((const void*)k_wc,
                            hipFuncAttributeMaxDynamicSharedMemorySize, 65536);

  k_prep <<<1280, 256, 0, stream>>>(Wff, Wv, Wo, Wc, wffb, wvb, wob, wcb);
  k_conv <<<2048, 512, 0, stream>>>(x, wffb, bff, outT, psum, psq);
  k_stats<<<256,  256, 0, stream>>>(psum, psq, mean, rstd);
  k_adj  <<<256,  256, 0, stream>>>(Wq, Wk, bq, bk, mean, rstd, wqkb, bqkp);
  k_v    <<<NT,   512, 0, stream>>>(f, wvb, bv, vbuf);
  k_qk   <<<NT,   512, 65536, stream>>>(outT, wqkb, bqkp, qT, ktb);
  k_attn <<<NB,   256, 0, stream>>>(qT, ktb, vbuf, wob, bo, mask, outT);
  k_wc   <<<NT,   512, 65536, stream>>>(outT, wcb, bc, x, mask, (float*)d_out);
}

// Round 6
// 357.129 us; speedup vs baseline: 1.1473x; 1.1473x over previous
//
#include <hip/hip_runtime.h>

#define L_LEN 131072
#define NB    2048     // 64-pos attention blocks
#define NT    1024     // 128-pos GEMM tiles

typedef unsigned short u16;
typedef __attribute__((ext_vector_type(4))) float f32x4;
typedef __attribute__((ext_vector_type(8))) short s16x8;
typedef __attribute__((ext_vector_type(4))) short s16x4;

// ---- ws byte offsets ----
#define WS_OUTT  0ull          // u16[L*256]  conv out, [pos][ch]; becomes hT in-place
#define WS_QT    67108864ull   // u16[L*128]  qT [pos][ch]
#define WS_PSUM  100663296ull  // float[256*1024]
#define WS_PSQ   101711872ull
#define WS_MEAN  102760448ull
#define WS_RSTD  102761472ull
#define WS_WFFB  102762496ull  // short[256*768] (k = t*256+c)
#define WS_WQKB  103155712ull  // short[256*256] rs-folded [Wq;Wk]
#define WS_WVB   103286784ull  // short[128*256]
#define WS_WOB   103352320ull  // short[256*128]
#define WS_WCB   103417856ull  // short[256*256]
#define WS_BQKP  103548928ull  // float[256]
// d_out regions (consumed before k_wc overwrites d_out):
//   v  u16[128*L] at byte 0 ; kT u16[L*128] at byte 33554432

__device__ __forceinline__ u16 f2bf(float v){
  union { float f; unsigned u; } a; a.f = v;
  unsigned r = a.u + 0x7fffu + ((a.u >> 16) & 1u);
  return (u16)(r >> 16);
}
__device__ __forceinline__ float bf2f(u16 u){
  union { unsigned u; float f; } a; a.u = ((unsigned)u) << 16; return a.f;
}
__device__ __forceinline__ unsigned cvtpk(float a, float b){
  unsigned r;
  asm("v_cvt_pk_bf16_f32 %0, %1, %2" : "=v"(r) : "v"(a), "v"(b));
  return r;
}
__device__ __forceinline__ f32x4 mfma16(s16x8 a, s16x8 b, f32x4 c){
  return __builtin_amdgcn_mfma_f32_16x16x32_bf16(a, b, c, 0, 0, 0);
}
__device__ __forceinline__ s16x8 ld8(const void* p){ return *(const s16x8*)p; }

// ---------------- K0: weight prep (fp32 -> bf16) ----------------
__global__ __launch_bounds__(256) void k_prep(
    const float* __restrict__ Wff, const float* __restrict__ Wv,
    const float* __restrict__ Wo,  const float* __restrict__ Wc,
    short* __restrict__ wffb, short* __restrict__ wvb,
    short* __restrict__ wob,  short* __restrict__ wcb)
{
  int i = blockIdx.x * 256 + threadIdx.x;
  if (i < 196608){
    int o = i / 768, kk = i % 768;
    int t = kk >> 8, c = kk & 255;
    wffb[i] = (short)f2bf(Wff[(o*256 + c)*3 + t]);
  } else if (i < 229376){ int j = i - 196608; wvb[j] = (short)f2bf(Wv[j]); }
  else if (i < 262144){ int j = i - 229376; wob[j] = (short)f2bf(Wo[j]); }
  else if (i < 327680){ int j = i - 262144; wcb[j] = (short)f2bf(Wc[j]); }
}

// ---------------- K1: dilated conv as GEMM -> outT[pos][ch] + stats ----------------
// tile: 256 och x 128 pos, K=768, tap-shared window staging (256 pos x 32 ch),
// double-buffered LDS, one barrier per chunk, 48 MFMA/wave/chunk.
// __launch_bounds__(512,2): 256-reg budget -> acc[2][8] + prefetch fit, no spill.
__global__ __launch_bounds__(512, 2) void k_conv(
    const float* __restrict__ x, const short* __restrict__ wffb,
    const float* __restrict__ bff, u16* __restrict__ outT,
    float* __restrict__ psum, float* __restrict__ psq)
{
  __shared__ u16 xs[2*256*40];         // 40KB
  const int wg = blockIdx.x, l0 = wg * 128;
  const int tid = threadIdx.x;
  const int w = tid >> 6, lane = tid & 63, p = lane & 15, g = lane >> 4;
  const int cl = tid >> 4, posq = tid & 15;   // staging roles: 32 ch x 16 pos-groups

  // prologue: stage chunk 0 into buf 0
  {
    #pragma unroll
    for (int u = 0; u < 4; ++u){
      const int row = 64*u + 4*posq;
      const long gp = (long)l0 - 64 + row;
      f32x4 v = {0.f,0.f,0.f,0.f};
      if (gp >= 0 && gp + 4 <= L_LEN)
        v = *(const f32x4*)(x + (size_t)cl*L_LEN + gp);
      const unsigned r01 = cvtpk(v[0], v[1]);
      const unsigned r23 = cvtpk(v[2], v[3]);
      xs[(row+0)*40 + (cl ^ (8*(((row+0)>>2)&3)))] = (u16)(r01 & 0xffffu);
      xs[(row+1)*40 + (cl ^ (8*(((row+1)>>2)&3)))] = (u16)(r01 >> 16);
      xs[(row+2)*40 + (cl ^ (8*(((row+2)>>2)&3)))] = (u16)(r23 & 0xffffu);
      xs[(row+3)*40 + (cl ^ (8*(((row+3)>>2)&3)))] = (u16)(r23 >> 16);
    }
  }
  __syncthreads();

  f32x4 acc[2][8] = {};
  #pragma unroll 1
  for (int cg = 0; cg < 8; ++cg){
    const int cur = (cg & 1) * 10240;
    const int nxt = ((cg + 1) & 1) * 10240;
    // issue next chunk's global loads (latency hides under MFMA phase)
    f32x4 vv[4];
    const bool have = (cg < 7);
    if (have){
      #pragma unroll
      for (int u = 0; u < 4; ++u){
        const int row = 64*u + 4*posq;
        const long gp = (long)l0 - 64 + row;
        vv[u] = f32x4{0.f,0.f,0.f,0.f};
        if (gp >= 0 && gp + 4 <= L_LEN)
          vv[u] = *(const f32x4*)(x + (size_t)((cg+1)*32 + cl)*L_LEN + gp);
      }
    }
    // MFMA phase: 3 taps x 8 fn x 2 fm = 48 MFMAs/wave
    #pragma unroll
    for (int t = 0; t < 3; ++t){
      s16x8 a0 = ld8(wffb + (size_t)(32*w +      p)*768 + t*256 + cg*32 + 8*g);
      s16x8 a1 = ld8(wffb + (size_t)(32*w + 16 + p)*768 + t*256 + cg*32 + 8*g);
      #pragma unroll
      for (int fn = 0; fn < 8; ++fn){
        const int row = 64*t + 16*fn + p;
        s16x8 b = ld8(&xs[cur + row*40 + ((8*g) ^ (8*((row>>2)&3)))]);
        acc[0][fn] = mfma16(a0, b, acc[0][fn]);
        acc[1][fn] = mfma16(a1, b, acc[1][fn]);
      }
    }
    // convert + store into the other buffer
    if (have){
      #pragma unroll
      for (int u = 0; u < 4; ++u){
        const int row = 64*u + 4*posq;
        const unsigned r01 = cvtpk(vv[u][0], vv[u][1]);
        const unsigned r23 = cvtpk(vv[u][2], vv[u][3]);
        xs[nxt + (row+0)*40 + (cl ^ (8*(((row+0)>>2)&3)))] = (u16)(r01 & 0xffffu);
        xs[nxt + (row+1)*40 + (cl ^ (8*(((row+1)>>2)&3)))] = (u16)(r01 >> 16);
        xs[nxt + (row+2)*40 + (cl ^ (8*(((row+2)>>2)&3)))] = (u16)(r23 & 0xffffu);
        xs[nxt + (row+3)*40 + (cl ^ (8*(((row+3)>>2)&3)))] = (u16)(r23 >> 16);
      }
    }
    __syncthreads();
  }
  // epilogue: bias+relu, store outT (packed), stats
  #pragma unroll
  for (int fm = 0; fm < 2; ++fm){
    const int o0 = 32*w + 16*fm + 4*g;
    float ssum[4] = {0,0,0,0}, ssq[4] = {0,0,0,0};
    #pragma unroll
    for (int fn = 0; fn < 8; ++fn){
      s16x4 pk;
      #pragma unroll
      for (int i = 0; i < 4; ++i){
        float val = fmaxf(acc[fm][fn][i] + bff[o0+i], 0.f);
        pk[i] = (short)f2bf(val);
        ssum[i] += val; ssq[i] += val*val;
      }
      *(s16x4*)(outT + (size_t)(l0 + 16*fn + p)*256 + o0) = pk;
    }
    #pragma unroll
    for (int i = 0; i < 4; ++i){
      float a = ssum[i], b = ssq[i];
      #pragma unroll
      for (int d = 1; d < 16; d <<= 1){ a += __shfl_xor(a, d, 16); b += __shfl_xor(b, d, 16); }
      if (p == 0){ psum[(size_t)(o0+i)*NT + wg] = a; psq[(size_t)(o0+i)*NT + wg] = b; }
    }
  }
}

// ---------------- K2: finalize stats ----------------
__global__ __launch_bounds__(256) void k_stats(
    const float* __restrict__ psum, const float* __restrict__ psq,
    float* __restrict__ mean, float* __restrict__ rstd)
{
  __shared__ float ss[256], sq[256];
  const int ch = blockIdx.x, tid = threadIdx.x;
  float a = 0.f, b = 0.f;
  for (int j = tid; j < NT; j += 256){ a += psum[(size_t)ch*NT + j]; b += psq[(size_t)ch*NT + j]; }
  ss[tid] = a; sq[tid] = b;
  __syncthreads();
  for (int st = 128; st > 0; st >>= 1){
    if (tid < st){ ss[tid] += ss[tid+st]; sq[tid] += sq[tid+st]; }
    __syncthreads();
  }
  if (tid == 0){
    float m = ss[0] / (float)L_LEN;
    float v = sq[0] / (float)L_LEN - m*m;
    mean[ch] = m;
    rstd[ch] = rsqrtf(v + 1e-5f);
  }
}

// ---------------- K3: fold norm into Wq/Wk ----------------
__global__ __launch_bounds__(256) void k_adj(
    const float* __restrict__ Wq, const float* __restrict__ Wk,
    const float* __restrict__ bq, const float* __restrict__ bk,
    const float* __restrict__ mean, const float* __restrict__ rstd,
    short* __restrict__ wqkb, float* __restrict__ bqkp)
{
  __shared__ float red[256];
  const int o = blockIdx.x, c = threadIdx.x;
  const float* src = (o < 128) ? (Wq + (size_t)o*256) : (Wk + (size_t)(o-128)*256);
  const float bias = (o < 128) ? bq[o] : bk[o-128];
  float wv = src[c] * rstd[c];
  wqkb[o*256 + c] = (short)f2bf(wv);
  red[c] = wv * mean[c];
  __syncthreads();
  for (int st = 128; st > 0; st >>= 1){
    if (c < st) red[c] += red[c+st];
    __syncthreads();
  }
  if (c == 0) bqkp[o] = bias - red[0];
}

// ---------------- K4: v = Wv @ f + bv -> v[128][L] ----------------
// 512 thr, wave = 16 cv x 128 pos: acc[8] = 32 regs. Double-buffered.
__global__ __launch_bounds__(512, 4) void k_v(
    const float* __restrict__ fin, const short* __restrict__ wvb,
    const float* __restrict__ bv, u16* __restrict__ vout)
{
  __shared__ u16 xs[2*128*40];         // 20KB
  const int wg = blockIdx.x, l0 = wg * 128;
  const int tid = threadIdx.x;
  const int w = tid >> 6, lane = tid & 63, p = lane & 15, g = lane >> 4;
  const int cl = tid >> 4, posq = tid & 15;   // 32 ch x 16 pos-groups (8 rows each)

  {
    #pragma unroll
    for (int u = 0; u < 2; ++u){
      const int row = 8*posq + 4*u;
      f32x4 v = *(const f32x4*)(fin + (size_t)cl*L_LEN + l0 + row);
      const unsigned r01 = cvtpk(v[0], v[1]);
      const unsigned r23 = cvtpk(v[2], v[3]);
      xs[(row+0)*40 + (cl ^ (8*(((row+0)>>2)&3)))] = (u16)(r01 & 0xffffu);
      xs[(row+1)*40 + (cl ^ (8*(((row+1)>>2)&3)))] = (u16)(r01 >> 16);
      xs[(row+2)*40 + (cl ^ (8*(((row+2)>>2)&3)))] = (u16)(r23 & 0xffffu);
      xs[(row+3)*40 + (cl ^ (8*(((row+3)>>2)&3)))] = (u16)(r23 >> 16);
    }
  }
  __syncthreads();

  f32x4 acc[8] = {};
  #pragma unroll 1
  for (int cg = 0; cg < 8; ++cg){
    const int cur = (cg & 1) * 5120;
    const int nxt = ((cg + 1) & 1) * 5120;
    f32x4 vv[2];
    const bool have = (cg < 7);
    if (have){
      #pragma unroll
      for (int u = 0; u < 2; ++u){
        const int row = 8*posq + 4*u;
        vv[u] = *(const f32x4*)(fin + (size_t)((cg+1)*32 + cl)*L_LEN + l0 + row);
      }
    }
    s16x8 af = ld8(wvb + (size_t)(16*w + p)*256 + cg*32 + 8*g);
    #pragma unroll
    for (int fn = 0; fn < 8; ++fn){
      const int row = 16*fn + p;
      s16x8 b = ld8(&xs[cur + row*40 + ((8*g) ^ (8*((row>>2)&3)))]);
      acc[fn] = mfma16(af, b, acc[fn]);
    }
    if (have){
      #pragma unroll
      for (int u = 0; u < 2; ++u){
        const int row = 8*posq + 4*u;
        const unsigned r01 = cvtpk(vv[u][0], vv[u][1]);
        const unsigned r23 = cvtpk(vv[u][2], vv[u][3]);
        xs[nxt + (row+0)*40 + (cl ^ (8*(((row+0)>>2)&3)))] = (u16)(r01 & 0xffffu);
        xs[nxt + (row+1)*40 + (cl ^ (8*(((row+1)>>2)&3)))] = (u16)(r01 >> 16);
        xs[nxt + (row+2)*40 + (cl ^ (8*(((row+2)>>2)&3)))] = (u16)(r23 & 0xffffu);
        xs[nxt + (row+3)*40 + (cl ^ (8*(((row+3)>>2)&3)))] = (u16)(r23 >> 16);
      }
    }
    __syncthreads();
  }
  #pragma unroll
  for (int fn = 0; fn < 8; ++fn){
    #pragma unroll
    for (int i = 0; i < 4; ++i){
      const int cv = 16*w + 4*g + i;
      vout[(size_t)cv*L_LEN + l0 + 16*fn + p] = f2bf(acc[fn][i] + bv[cv]);
    }
  }
}

// ---------------- K5: [q;k] = Wqk' @ out + bqk' -> qT, kT ----------------
__global__ __launch_bounds__(512, 2) void k_qk(
    const u16* __restrict__ outT, const short* __restrict__ wqkb,
    const float* __restrict__ bqkp, u16* __restrict__ qT, u16* __restrict__ kT)
{
  extern __shared__ u16 tile[];        // [128 pos][256 ch] swizzled, 64KB
  const int wg = blockIdx.x, l0 = wg * 128;
  const int tid = threadIdx.x;
  const int w = tid >> 6, lane = tid & 63, p = lane & 15, g = lane >> 4;
  #pragma unroll
  for (int rep = 0; rep < 8; ++rep){
    const int idx = rep*512 + tid;
    const int r = idx >> 5, cc = idx & 31;
    s16x8 vput = ld8(outT + (size_t)(l0 + r)*256 + cc*8);
    *(s16x8*)(&tile[r*256 + ((cc*8) ^ ((r&7)<<3))]) = vput;
  }
  __syncthreads();
  f32x4 acc[2][8] = {};
  #pragma unroll
  for (int kk = 0; kk < 8; ++kk){
    s16x8 af[2];
    af[0] = ld8(wqkb + (size_t)(32*w +      p)*256 + 32*kk + 8*g);
    af[1] = ld8(wqkb + (size_t)(32*w + 16 + p)*256 + 32*kk + 8*g);
    #pragma unroll
    for (int fn = 0; fn < 8; ++fn){
      const int r = 16*fn + p;
      s16x8 b = ld8(&tile[r*256 + ((32*kk + 8*g) ^ ((r&7)<<3))]);
      acc[0][fn] = mfma16(af[0], b, acc[0][fn]);
      acc[1][fn] = mfma16(af[1], b, acc[1][fn]);
    }
  }
  #pragma unroll
  for (int fm = 0; fm < 2; ++fm){
    const int R0 = 32*w + 16*fm + 4*g;
    #pragma unroll
    for (int fn = 0; fn < 8; ++fn){
      s16x4 pk;
      #pragma unroll
      for (int i = 0; i < 4; ++i) pk[i] = (short)f2bf(acc[fm][fn][i] + bqkp[R0+i]);
      const size_t row = (size_t)(l0 + 16*fn + p);
      if (R0 < 128) *(s16x4*)(qT + row*128 + R0)       = pk;
      else          *(s16x4*)(kT + row*128 + R0 - 128) = pk;
    }
  }
}

// ---------------- K6: attention per 64-block + Wo; h in-place over outT ----------------
__global__ __launch_bounds__(256, 4) void k_attn(
    const u16* __restrict__ qT, const u16* __restrict__ kT,
    const u16* __restrict__ vg, const short* __restrict__ wob,
    const float* __restrict__ bo, const float* __restrict__ mask,
    u16* __restrict__ outT)
{
  __shared__ u16 klds[16384];          // 32KB: k-window; overlays: p [0,8K), rov [8K,16K)
  __shared__ float maskw[128];
  const int tid = threadIdx.x;
  const int w = tid >> 6, lane = tid & 63, p = lane & 15, g = lane >> 4;
  const int n = blockIdx.x, s = n * 64;
  const float SCALE = 0.08838834764831845f;

  #pragma unroll
  for (int rep = 0; rep < 8; ++rep){
    const int idx = rep*256 + tid;
    const int m = idx >> 4, cc = idx & 15;
    const int gpos = s - 32 + m;
    s16x8 vput = {};
    if (gpos >= 0 && gpos < L_LEN) vput = ld8(kT + (size_t)gpos*128 + cc*8);
    *(s16x8*)(&klds[m*128 + ((cc*8) ^ ((m&7)<<3))]) = vput;
  }
  if (tid < 128){
    const int gp = s - 32 + tid;
    maskw[tid] = (gp >= 0 && gp < L_LEN) ? mask[gp] : 0.f;
  }
  __syncthreads();

  f32x4 e[8] = {};
  #pragma unroll
  for (int kk = 0; kk < 4; ++kk){
    s16x8 aq = ld8(qT + (size_t)(s + 16*w + p)*128 + 32*kk + 8*g);
    #pragma unroll
    for (int fn = 0; fn < 8; ++fn){
      const int m = 16*fn + p;
      s16x8 b = ld8(&klds[m*128 + ((32*kk + 8*g) ^ ((m&7)<<3))]);
      e[fn] = mfma16(aq, b, e[fn]);
    }
  }
  float M[4] = {-1e30f,-1e30f,-1e30f,-1e30f};
  float S[4] = {0.f,0.f,0.f,0.f};
  #pragma unroll
  for (int fn = 0; fn < 8; ++fn){
    #pragma unroll
    for (int i = 0; i < 4; ++i){
      const int mm = 16*fn + p;
      const int l_ = 16*w + 4*g + i;
      const int d = mm - l_;
      const float fmv = (d >= 0 && d < 64) ? maskw[mm] : 0.f;
      const float z = e[fn][i]*SCALE + __logf(fmv + 1e-6f);
      e[fn][i] = z;
      M[i] = fmaxf(M[i], z);
    }
  }
  #pragma unroll
  for (int i = 0; i < 4; ++i){
    #pragma unroll
    for (int d = 1; d < 16; d <<= 1) M[i] = fmaxf(M[i], __shfl_xor(M[i], d, 16));
  }
  #pragma unroll
  for (int fn = 0; fn < 8; ++fn){
    #pragma unroll
    for (int i = 0; i < 4; ++i){
      const float pv = __expf(e[fn][i] - M[i]);
      e[fn][i] = pv;
      S[i] += pv;
    }
  }
  #pragma unroll
  for (int i = 0; i < 4; ++i){
    #pragma unroll
    for (int d = 1; d < 16; d <<= 1) S[i] += __shfl_xor(S[i], d, 16);
  }
  float rinv[4];
  #pragma unroll
  for (int i = 0; i < 4; ++i) rinv[i] = 1.f / S[i];
  __syncthreads();
  #pragma unroll
  for (int fn = 0; fn < 8; ++fn){
    #pragma unroll
    for (int i = 0; i < 4; ++i){
      const int mm = 16*fn + p;
      const int l_ = 16*w + 4*g + i;
      const int d = mm - l_;
      const float fmv = (d >= 0 && d < 64) ? maskw[mm] : 0.f;
      klds[l_*128 + (mm ^ ((l_&7)<<3))] = f2bf(e[fn][i] * rinv[i] * fmv);
    }
  }
  __syncthreads();

  f32x4 accp[2][4] = {};
  #pragma unroll
  for (int kk = 0; kk < 4; ++kk){
    int gp0 = s - 32 + 32*kk + 8*g;
    gp0 = max(0, min(gp0, L_LEN - 8));
    s16x8 a0 = ld8(vg + (size_t)(32*w +      p)*L_LEN + gp0);
    s16x8 a1 = ld8(vg + (size_t)(32*w + 16 + p)*L_LEN + gp0);
    #pragma unroll
    for (int fn = 0; fn < 4; ++fn){
      const int l_ = 16*fn + p;
      s16x8 b = ld8(&klds[l_*128 + ((32*kk + 8*g) ^ ((l_&7)<<3))]);
      accp[0][fn] = mfma16(a0, b, accp[0][fn]);
      accp[1][fn] = mfma16(a1, b, accp[1][fn]);
    }
  }
  #pragma unroll
  for (int fm = 0; fm < 2; ++fm){
    #pragma unroll
    for (int fn = 0; fn < 4; ++fn){
      const int l_ = 16*fn + p;
      s16x4 pk;
      #pragma unroll
      for (int i = 0; i < 4; ++i) pk[i] = (short)f2bf(fmaxf(accp[fm][fn][i], 0.f));
      const int cv0 = 32*w + 16*fm + 4*g;
      *(s16x4*)(&klds[8192 + l_*128 + (cv0 ^ ((l_&7)<<3))]) = pk;
    }
  }
  __syncthreads();

  f32x4 acco[4][4] = {};
  #pragma unroll
  for (int kk = 0; kk < 4; ++kk){
    s16x8 a[4];
    #pragma unroll
    for (int fm = 0; fm < 4; ++fm)
      a[fm] = ld8(wob + (size_t)(64*w + 16*fm + p)*128 + 32*kk + 8*g);
    #pragma unroll
    for (int fn = 0; fn < 4; ++fn){
      const int l_ = 16*fn + p;
      s16x8 b = ld8(&klds[8192 + l_*128 + ((32*kk + 8*g) ^ ((l_&7)<<3))]);
      #pragma unroll
      for (int fm = 0; fm < 4; ++fm) acco[fm][fn] = mfma16(a[fm], b, acco[fm][fn]);
    }
  }
  #pragma unroll
  for (int fm = 0; fm < 4; ++fm){
    const int o0 = 64*w + 16*fm + 4*g;
    #pragma unroll
    for (int fn = 0; fn < 4; ++fn){
      const int l_ = 16*fn + p;
      const float pml = maskw[32 + l_];
      u16* hp = outT + (size_t)(s + l_)*256 + o0;
      s16x4 res = *(const s16x4*)hp;
      s16x4 pk;
      #pragma unroll
      for (int i = 0; i < 4; ++i){
        float hv = (acco[fm][fn][i] + bo[o0+i]) * pml + bf2f((u16)res[i]);
        pk[i] = (short)f2bf(hv);
      }
      *(s16x4*)hp = pk;
    }
  }
}

// ---------------- K7: y = Wc @ h + bc; dout = (x + y) * mask ----------------
__global__ __launch_bounds__(512, 2) void k_wc(
    const u16* __restrict__ hT, const short* __restrict__ wcb,
    const float* __restrict__ bc, const float* __restrict__ x,
    const float* __restrict__ mask, float* __restrict__ dout)
{
  extern __shared__ u16 tile[];
  const int wg = blockIdx.x, l0 = wg * 128;
  const int tid = threadIdx.x;
  const int w = tid >> 6, lane = tid & 63, p = lane & 15, g = lane >> 4;
  #pragma unroll
  for (int rep = 0; rep < 8; ++rep){
    const int idx = rep*512 + tid;
    const int r = idx >> 5, cc = idx & 31;
    s16x8 vput = ld8(hT + (size_t)(l0 + r)*256 + cc*8);
    *(s16x8*)(&tile[r*256 + ((cc*8) ^ ((r&7)<<3))]) = vput;
  }
  __syncthreads();
  f32x4 acc[2][8] = {};
  #pragma unroll
  for (int kk = 0; kk < 8; ++kk){
    s16x8 af[2];
    af[0] = ld8(wcb + (size_t)(32*w +      p)*256 + 32*kk + 8*g);
    af[1] = ld8(wcb + (size_t)(32*w + 16 + p)*256 + 32*kk + 8*g);
    #pragma unroll
    for (int fn = 0; fn < 8; ++fn){
      const int r = 16*fn + p;
      s16x8 b = ld8(&tile[r*256 + ((32*kk + 8*g) ^ ((r&7)<<3))]);
      acc[0][fn] = mfma16(af[0], b, acc[0][fn]);
      acc[1][fn] = mfma16(af[1], b, acc[1][fn]);
    }
  }
  #pragma unroll
  for (int fm = 0; fm < 2; ++fm){
    const int o0 = 32*w + 16*fm + 4*g;
    #pragma unroll
    for (int fn = 0; fn < 8; ++fn){
      const int pos = l0 + 16*fn + p;
      const float mk = mask[pos];
      #pragma unroll
      for (int i = 0; i < 4; ++i){
        const size_t idx = (size_t)(o0+i)*L_LEN + pos;
        dout[idx] = (x[idx] + acc[fm][fn][i] + bc[o0+i]) * mk;
      }
    }
  }
}

extern "C" void kernel_launch(void* const* d_in, const int* in_sizes, int n_in,
                              void* d_out, int out_size, void* d_ws, size_t ws_size,
                              hipStream_t stream)
{
  (void)in_sizes; (void)n_in; (void)out_size; (void)ws_size;
  const float* x    = (const float*)d_in[0];
  const float* f    = (const float*)d_in[1];
  const float* mask = (const float*)d_in[2];
  const float* Wff  = (const float*)d_in[3];
  const float* bff  = (const float*)d_in[4];
  const float* Wq   = (const float*)d_in[5];
  const float* bq   = (const float*)d_in[6];
  const float* Wk   = (const float*)d_in[7];
  const float* bk   = (const float*)d_in[8];
  const float* Wv   = (const float*)d_in[9];
  const float* bv   = (const float*)d_in[10];
  const float* Wo   = (const float*)d_in[11];
  const float* bo   = (const float*)d_in[12];
  const float* Wc   = (const float*)d_in[13];
  const float* bc   = (const float*)d_in[14];

  char* ws = (char*)d_ws;
  u16*   outT = (u16*)(ws + WS_OUTT);
  u16*   qT   = (u16*)(ws + WS_QT);
  float* psum = (float*)(ws + WS_PSUM);
  float* psq  = (float*)(ws + WS_PSQ);
  float* mean = (float*)(ws + WS_MEAN);
  float* rstd = (float*)(ws + WS_RSTD);
  short* wffb = (short*)(ws + WS_WFFB);
  short* wqkb = (short*)(ws + WS_WQKB);
  short* wvb  = (short*)(ws + WS_WVB);
  short* wob  = (short*)(ws + WS_WOB);
  short* wcb  = (short*)(ws + WS_WCB);
  float* bqkp = (float*)(ws + WS_BQKP);

  u16* vbuf = (u16*)d_out;                       // v[128][L]
  u16* ktb  = (u16*)((char*)d_out + 33554432);   // kT[L][128]

  (void)hipFuncSetAttribute((const void*)k_qk,
                            hipFuncAttributeMaxDynamicSharedMemorySize, 65536);
  (void)hipFuncSetAttribute((const void*)k_wc,
                            hipFuncAttributeMaxDynamicSharedMemorySize, 65536);

  k_prep <<<1280, 256, 0, stream>>>(Wff, Wv, Wo, Wc, wffb, wvb, wob, wcb);
  k_conv <<<NT,   512, 0, stream>>>(x, wffb, bff, outT, psum, psq);
  k_stats<<<256,  256, 0, stream>>>(psum, psq, mean, rstd);
  k_adj  <<<256,  256, 0, stream>>>(Wq, Wk, bq, bk, mean, rstd, wqkb, bqkp);
  k_v    <<<NT,   512, 0, stream>>>(f, wvb, bv, vbuf);
  k_qk   <<<NT,   512, 65536, stream>>>(outT, wqkb, bqkp, qT, ktb);
  k_attn <<<NB,   256, 0, stream>>>(qT, ktb, vbuf, wob, bo, mask, outT);
  k_wc   <<<NT,   512, 65536, stream>>>(outT, wcb, bc, x, mask, (float*)d_out);
}